// Round 3
// baseline (731.212 us; speedup 1.0000x reference)
//
#include <hip/hip_runtime.h>

// Entropic Sinkhorn EMD, B=2, N=4096, D=3, EPS=0.1, 20 iters.
// Round-3: same register-resident j-points structure as round-2, but with an
// inline-asm opaque barrier on every loaded j-value so the compiler CANNOT
// rematerialize the loads inside the row loop (round-2 showed VGPR_Count=28,
// i.e. the j-arrays were re-fetched per row -> latency-bound at VALUBusy=16%).
// __launch_bounds__(512, 2) lifts the register cap the heuristic was chasing.

#define N   4096
#define NT  512     // 8 waves/block
#define IC  16      // rows per block -> grid.x = 256, 512 blocks total
#define JPL 8       // j's per lane (8 waves x 64 lanes x 8 = 4096 per block)

// Zero-instruction opaque: pins v in a VGPR, kills rematerialization/sinking.
#define OPAQUE(v) asm volatile("" : "+v"(v))

constexpr float EPS_F = 0.1f;
constexpr float SHIFT = 60.0f;
constexpr float LOG_A = -8.317766166719343f;   // -log(4096)
constexpr float L2E   = 1.4426950408889634f;   // log2(e)
constexpr float C10L  = 14.426950408889634f;   // 10*log2(e)
constexpr float C20L  = 28.853900817779268f;   // 20*log2(e)
constexpr float NLN2T = -0.06931471805599453f; // -ln2/10  (pack w -> |p|^2)
constexpr float LN2   = 0.6931471805599453f;

// Pack {x,y,z, -10*L2E*|p|^2} for both clouds; zero f,g and out.
__global__ __launch_bounds__(256) void prep_kernel(
    const float* __restrict__ gen, const float* __restrict__ gt,
    float4* __restrict__ genPack, float4* __restrict__ gtPack,
    float* __restrict__ fg, float* __restrict__ out)
{
    int t = blockIdx.x * 256 + threadIdx.x;   // 0 .. 16383
    int cloud = t >> 13;
    int idx   = t & 8191;                     // b*N + j
    const float* src = cloud ? gt : gen;
    float x = src[idx * 3 + 0];
    float y = src[idx * 3 + 1];
    float z = src[idx * 3 + 2];
    float w = -C10L * fmaf(z, z, fmaf(y, y, x * x));
    (cloud ? gtPack : genPack)[idx] = make_float4(x, y, z, w);
    fg[t] = 0.0f;                             // f[2][N] then g[2][N]
    if (t == 0) out[0] = 0.0f;
}

// Half-sweep: dualRowOut_i = EPS*(LOG_A + SHIFT - ln sum_j 2^{arg})
// arg = 20L*pi.pj + h2_j + s2_i   (all pre-scaled to log2 units)
__global__ __launch_bounds__(NT, 2) void sweep_kernel(
    const float4* __restrict__ rowPack,
    const float4* __restrict__ colPack,
    const float*  __restrict__ dualCol,
    float*        __restrict__ dualRowOut)
{
    __shared__ float sPart[IC][8];

    const int b    = blockIdx.y;
    const int tid  = threadIdx.x;
    const int wave = tid >> 6;
    const int lane = tid & 63;
    const int jbase = wave * (64 * JPL) + lane;

    float xj[JPL], yj[JPL], zj[JPL], h2[JPL];
    {
        const float4* cp = colPack + (size_t)b * N;
        const float*  dc = dualCol + (size_t)b * N;
        #pragma unroll
        for (int m = 0; m < JPL; ++m) {
            float4 p = cp[jbase + 64 * m];
            float  g = dc[jbase + 64 * m];
            xj[m] = p.x; yj[m] = p.y; zj[m] = p.z;
            h2[m] = fmaf(g, C10L, (SHIFT * L2E) + p.w);
            OPAQUE(xj[m]); OPAQUE(yj[m]); OPAQUE(zj[m]); OPAQUE(h2[m]);
        }
    }

    const float4* rp = rowPack + (size_t)b * N + (size_t)blockIdx.x * IC;

    #pragma unroll 2
    for (int ii = 0; ii < IC; ++ii) {
        float4 q = rp[ii];
        float X = q.x * C20L;
        float Y = q.y * C20L;
        float Z = q.z * C20L;
        float s2 = q.w;                    // -10*L2E*|pi|^2
        float a0 = 0.f, a1 = 0.f, a2 = 0.f, a3 = 0.f;
        #pragma unroll
        for (int m = 0; m < JPL; m += 4) {
            a0 += exp2f(fmaf(X, xj[m+0], fmaf(Y, yj[m+0], fmaf(Z, zj[m+0], h2[m+0] + s2))));
            a1 += exp2f(fmaf(X, xj[m+1], fmaf(Y, yj[m+1], fmaf(Z, zj[m+1], h2[m+1] + s2))));
            a2 += exp2f(fmaf(X, xj[m+2], fmaf(Y, yj[m+2], fmaf(Z, zj[m+2], h2[m+2] + s2))));
            a3 += exp2f(fmaf(X, xj[m+3], fmaf(Y, yj[m+3], fmaf(Z, zj[m+3], h2[m+3] + s2))));
        }
        float sum = (a0 + a1) + (a2 + a3);
        sum += __shfl_xor(sum, 1);
        sum += __shfl_xor(sum, 2);
        sum += __shfl_xor(sum, 4);
        sum += __shfl_xor(sum, 8);
        sum += __shfl_xor(sum, 16);
        sum += __shfl_xor(sum, 32);
        if (lane == 0) sPart[ii][wave] = sum;
    }
    __syncthreads();

    if (tid < IC) {
        float t = 0.f;
        #pragma unroll
        for (int w = 0; w < 8; ++w) t += sPart[tid][w];
        dualRowOut[(size_t)b * N + (size_t)blockIdx.x * IC + tid] =
            EPS_F * (LOG_A + SHIFT - log2f(t) * LN2);
    }
}

// loss += 0.5 * sum_ij exp((f_i + g_j - C_ij)/EPS) * C_ij
__global__ __launch_bounds__(NT, 2) void loss_kernel(
    const float4* __restrict__ rowPack,   // gen pack
    const float4* __restrict__ colPack,   // gt pack
    const float*  __restrict__ f,
    const float*  __restrict__ g,
    float*        __restrict__ out)
{
    const int b    = blockIdx.y;
    const int tid  = threadIdx.x;
    const int wave = tid >> 6;
    const int lane = tid & 63;
    const int jbase = wave * (64 * JPL) + lane;

    float xj[JPL], yj[JPL], zj[JPL], rj[JPL], G2[JPL];
    {
        const float4* cp = colPack + (size_t)b * N;
        const float*  gc = g + (size_t)b * N;
        #pragma unroll
        for (int m = 0; m < JPL; ++m) {
            float4 p = cp[jbase + 64 * m];
            float  gv = gc[jbase + 64 * m];
            xj[m] = p.x; yj[m] = p.y; zj[m] = p.z;
            rj[m] = p.w * NLN2T;          // |pj|^2
            G2[m] = gv * C10L;
            OPAQUE(xj[m]); OPAQUE(yj[m]); OPAQUE(zj[m]); OPAQUE(rj[m]); OPAQUE(G2[m]);
        }
    }

    const float4* rp = rowPack + (size_t)b * N + (size_t)blockIdx.x * IC;
    const float*  fp = f + (size_t)b * N + (size_t)blockIdx.x * IC;

    float acc0 = 0.f, acc1 = 0.f, acc2 = 0.f, acc3 = 0.f;
    #pragma unroll 2
    for (int ii = 0; ii < IC; ++ii) {
        float4 q = rp[ii];
        float ri = q.w * NLN2T;            // |pi|^2
        float F2 = fp[ii] * C10L;
        #pragma unroll
        for (int m = 0; m < JPL; m += 4) {
            {
                float d  = fmaf(q.x, xj[m+0], fmaf(q.y, yj[m+0], q.z * zj[m+0]));
                float cc = fmaf(-2.f, d, ri + rj[m+0]);
                float p  = exp2f(fmaf(cc, -C10L, F2 + G2[m+0]));
                acc0 = fmaf(p, cc, acc0);
            }
            {
                float d  = fmaf(q.x, xj[m+1], fmaf(q.y, yj[m+1], q.z * zj[m+1]));
                float cc = fmaf(-2.f, d, ri + rj[m+1]);
                float p  = exp2f(fmaf(cc, -C10L, F2 + G2[m+1]));
                acc1 = fmaf(p, cc, acc1);
            }
            {
                float d  = fmaf(q.x, xj[m+2], fmaf(q.y, yj[m+2], q.z * zj[m+2]));
                float cc = fmaf(-2.f, d, ri + rj[m+2]);
                float p  = exp2f(fmaf(cc, -C10L, F2 + G2[m+2]));
                acc2 = fmaf(p, cc, acc2);
            }
            {
                float d  = fmaf(q.x, xj[m+3], fmaf(q.y, yj[m+3], q.z * zj[m+3]));
                float cc = fmaf(-2.f, d, ri + rj[m+3]);
                float p  = exp2f(fmaf(cc, -C10L, F2 + G2[m+3]));
                acc3 = fmaf(p, cc, acc3);
            }
        }
    }
    float acc = (acc0 + acc1) + (acc2 + acc3);
    acc += __shfl_xor(acc, 1);
    acc += __shfl_xor(acc, 2);
    acc += __shfl_xor(acc, 4);
    acc += __shfl_xor(acc, 8);
    acc += __shfl_xor(acc, 16);
    acc += __shfl_xor(acc, 32);
    if (lane == 0) atomicAdd(out, acc * 0.5f);
}

extern "C" void kernel_launch(void* const* d_in, const int* in_sizes, int n_in,
                              void* d_out, int out_size, void* d_ws, size_t ws_size,
                              hipStream_t stream) {
    const float* gen = (const float*)d_in[0];
    const float* gt  = (const float*)d_in[1];
    float* out = (float*)d_out;

    char* ws = (char*)d_ws;
    float4* genPack = (float4*)ws;                       // 128 KB
    float4* gtPack  = (float4*)(ws + 128 * 1024);        // 128 KB
    float*  f       = (float*)(ws + 256 * 1024);         // 32 KB (f then g)
    float*  g       = f + 2 * N;

    prep_kernel<<<dim3(16384 / 256), 256, 0, stream>>>(gen, gt, genPack, gtPack, f, out);

    const dim3 grid(N / IC, 2);   // 256 x 2 = 512 blocks
    for (int it = 0; it < 20; ++it) {
        sweep_kernel<<<grid, NT, 0, stream>>>(genPack, gtPack, g, f);
        sweep_kernel<<<grid, NT, 0, stream>>>(gtPack, genPack, f, g);
    }
    loss_kernel<<<grid, NT, 0, stream>>>(genPack, gtPack, f, g, out);
}

// Round 4
// 579.297 us; speedup vs baseline: 1.2622x; 1.2622x over previous
//
#include <hip/hip_runtime.h>

// Entropic Sinkhorn EMD, B=2, N=4096, D=3, EPS=0.1, 20 iters.
// Round-4: row constants in SGPRs (8 rows/block, forced via readfirstlane),
// j-data streamed as ONE float4 per j from L2 (pack.w carries h2, updated by
// the previous sweep's epilogue). Inner loop: 6 VALU instr/pair, no LDS, no
// per-row refetch -> VALU-bound by construction. Rounds 2-3 failed because
// per-LANE j-residency was spilled by the allocator (VGPR_Count=28); SGPRs
// cannot be spilled into the hot loop and cost 0 VGPRs.

#define N   4096
#define NT  256
#define RPB 8      // rows per block -> grid.x = 512, 1024 blocks total

constexpr float EPS_F  = 0.1f;
constexpr float SHIFT  = 60.0f;
constexpr float LOG_A  = -8.317766166719343f;   // -log(4096)
constexpr float L2E    = 1.4426950408889634f;   // log2(e)
constexpr float C10L   = 14.426950408889634f;   // 10*log2(e)
constexpr float C20L   = 28.853900817779268f;   // 20*log2(e)
constexpr float SHIFTL = 86.56170245333781f;    // SHIFT*L2E
constexpr float NLN2T  = -0.06931471805599453f; // -ln2/10
constexpr float LN2    = 0.6931471805599453f;

__device__ __forceinline__ float rfl(float x) {
    return __int_as_float(__builtin_amdgcn_readfirstlane(__float_as_int(x)));
}

// Pack {x,y,z, h2(g=0) = SHIFTL - 10L|p|^2}; wBase = -10L|p|^2; zero f,g,out.
__global__ __launch_bounds__(256) void prep_kernel(
    const float* __restrict__ gen, const float* __restrict__ gt,
    float4* __restrict__ genPack, float4* __restrict__ gtPack,
    float* __restrict__ wBaseGen, float* __restrict__ wBaseGt,
    float* __restrict__ fg, float* __restrict__ out)
{
    int t = blockIdx.x * 256 + threadIdx.x;   // 0 .. 16383
    int cloud = t >> 13;
    int idx   = t & 8191;                     // b*N + j
    const float* src = cloud ? gt : gen;
    float x = src[idx * 3 + 0];
    float y = src[idx * 3 + 1];
    float z = src[idx * 3 + 2];
    float nb = -C10L * fmaf(z, z, fmaf(y, y, x * x));   // -10L|p|^2
    (cloud ? gtPack : genPack)[idx] = make_float4(x, y, z, SHIFTL + nb);
    (cloud ? wBaseGt : wBaseGen)[idx] = nb;
    fg[t] = 0.0f;                             // f[2][N] then g[2][N]
    if (t == 0) out[0] = 0.0f;
}

// Half-sweep. Rows = packRow's cloud (8 per block, constants in SGPRs);
// columns streamed from packCol (w field = current h2 of the column dual).
// Epilogue writes the new raw dual AND refreshes packRow.w = new h2, so the
// next sweep (where this cloud is the column) reads one float4 per j.
__global__ __launch_bounds__(NT, 8) void sweep_kernel(
    float4*       __restrict__ packRow,   // [2][N]
    const float4* __restrict__ packCol,   // [2][N]
    const float*  __restrict__ wBaseRow,  // [2][N]
    float*        __restrict__ dualRaw)   // [2][N]
{
    const int b   = blockIdx.y;
    const int tid = threadIdx.x;
    const int rowBase = blockIdx.x * RPB;

    float4*      rp = packRow  + (size_t)b * N + rowBase;
    const float* wb = wBaseRow + (size_t)b * N + rowBase;

    float X[RPB], Y[RPB], Z[RPB], S[RPB];
    #pragma unroll
    for (int r = 0; r < RPB; ++r) {
        float4 q = rp[r];
        X[r] = rfl(q.x * C20L);
        Y[r] = rfl(q.y * C20L);
        Z[r] = rfl(q.z * C20L);
        S[r] = rfl(wb[r]);                 // -10L|p_i|^2
    }

    const float4* cp = packCol + (size_t)b * N;

    float acc[RPB];
    #pragma unroll
    for (int r = 0; r < RPB; ++r) acc[r] = 0.0f;

    #pragma unroll 2
    for (int k = 0; k < N / NT; ++k) {
        float4 p = cp[tid + NT * k];       // {xj, yj, zj, h2j}
        #pragma unroll
        for (int r = 0; r < RPB; ++r) {
            float t = fmaf(Z[r], p.z, p.w);
            t = fmaf(Y[r], p.y, t);
            t = fmaf(X[r], p.x, t);
            t = t + S[r];
            acc[r] += exp2f(t);
        }
    }

    // Reduce each row-sum across the block: wave shuffle + tiny LDS.
    #pragma unroll
    for (int r = 0; r < RPB; ++r) {
        float a = acc[r];
        a += __shfl_xor(a, 32);
        a += __shfl_xor(a, 16);
        a += __shfl_xor(a, 8);
        a += __shfl_xor(a, 4);
        a += __shfl_xor(a, 2);
        a += __shfl_xor(a, 1);
        acc[r] = a;
    }
    __shared__ float sred[RPB][4];
    const int wave = tid >> 6, lane = tid & 63;
    if (lane == 0) {
        #pragma unroll
        for (int r = 0; r < RPB; ++r) sred[r][wave] = acc[r];
    }
    __syncthreads();
    if (tid < RPB) {
        float s = (sred[tid][0] + sred[tid][1]) + (sred[tid][2] + sred[tid][3]);
        float dual = EPS_F * (LOG_A + SHIFT - log2f(s) * LN2);
        dualRaw[(size_t)b * N + rowBase + tid] = dual;
        // refresh h2 for when this cloud serves as the column next sweep
        ((float*)(rp + tid))[3] = fmaf(dual, C10L, SHIFTL + wb[tid]);
    }
}

// loss += 0.5 * sum_ij exp((f_i + g_j - C_ij)/EPS) * C_ij
__global__ __launch_bounds__(NT, 8) void loss_kernel(
    const float4* __restrict__ packGen,   // rows
    const float4* __restrict__ packGt,    // columns
    const float*  __restrict__ wBaseGen,
    const float*  __restrict__ f,
    const float*  __restrict__ g,
    float*        __restrict__ out)
{
    const int b   = blockIdx.y;
    const int tid = threadIdx.x;
    const int rowBase = blockIdx.x * RPB;

    const float4* rp = packGen  + (size_t)b * N + rowBase;
    const float*  wb = wBaseGen + (size_t)b * N + rowBase;
    const float*  fp = f        + (size_t)b * N + rowBase;

    float Ax[RPB], Ay[RPB], Az[RPB], Ri[RPB], F2[RPB];
    #pragma unroll
    for (int r = 0; r < RPB; ++r) {
        float4 q = rp[r];
        Ax[r] = rfl(q.x * -2.0f);
        Ay[r] = rfl(q.y * -2.0f);
        Az[r] = rfl(q.z * -2.0f);
        Ri[r] = rfl(wb[r] * NLN2T);        // |p_i|^2
        F2[r] = rfl(fp[r] * C10L);
    }

    const float4* cp = packGt + (size_t)b * N;
    const float*  gc = g      + (size_t)b * N;

    float acc = 0.0f;
    #pragma unroll 2
    for (int k = 0; k < N / NT; ++k) {
        float4 p  = cp[tid + NT * k];
        float  gj = gc[tid + NT * k];
        float  G2 = gj * C10L;
        float  rj = fmaf(p.w - SHIFTL, NLN2T, gj);   // |p_j|^2
        #pragma unroll
        for (int r = 0; r < RPB; ++r) {
            float cc = rj + Ri[r];
            cc = fmaf(Az[r], p.z, cc);
            cc = fmaf(Ay[r], p.y, cc);
            cc = fmaf(Ax[r], p.x, cc);
            float arg = fmaf(cc, -C10L, G2 + F2[r]);
            acc = fmaf(exp2f(arg), cc, acc);
        }
    }

    acc += __shfl_xor(acc, 32);
    acc += __shfl_xor(acc, 16);
    acc += __shfl_xor(acc, 8);
    acc += __shfl_xor(acc, 4);
    acc += __shfl_xor(acc, 2);
    acc += __shfl_xor(acc, 1);
    __shared__ float sred[4];
    const int wave = tid >> 6, lane = tid & 63;
    if (lane == 0) sred[wave] = acc;
    __syncthreads();
    if (tid == 0) {
        float t = (sred[0] + sred[1]) + (sred[2] + sred[3]);
        atomicAdd(out, t * 0.5f);
    }
}

extern "C" void kernel_launch(void* const* d_in, const int* in_sizes, int n_in,
                              void* d_out, int out_size, void* d_ws, size_t ws_size,
                              hipStream_t stream) {
    const float* gen = (const float*)d_in[0];
    const float* gt  = (const float*)d_in[1];
    float* out = (float*)d_out;

    char* ws = (char*)d_ws;
    float4* genPack  = (float4*)ws;                        // 128 KB
    float4* gtPack   = (float4*)(ws + 128 * 1024);         // 128 KB
    float*  wBaseGen = (float*)(ws + 256 * 1024);          // 32 KB
    float*  wBaseGt  = (float*)(ws + 288 * 1024);          // 32 KB
    float*  f        = (float*)(ws + 320 * 1024);          // 32 KB (f then g)
    float*  g        = f + 2 * N;

    prep_kernel<<<dim3(16384 / 256), 256, 0, stream>>>(
        gen, gt, genPack, gtPack, wBaseGen, wBaseGt, f, out);

    const dim3 grid(N / RPB, 2);   // 512 x 2 = 1024 blocks
    for (int it = 0; it < 20; ++it) {
        // f update: rows = gen, cols = gt (reads gtPack.w = h2(g)), writes f + genPack.w
        sweep_kernel<<<grid, NT, 0, stream>>>(genPack, gtPack, wBaseGen, f);
        // g update: rows = gt, cols = gen (reads genPack.w = h2(f)), writes g + gtPack.w
        sweep_kernel<<<grid, NT, 0, stream>>>(gtPack, genPack, wBaseGt, g);
    }
    loss_kernel<<<grid, NT, 0, stream>>>(genPack, gtPack, wBaseGen, f, g, out);
}